// Round 5
// baseline (332.848 us; speedup 1.0000x reference)
//
#include <hip/hip_runtime.h>
#include <math.h>

// Fused dual-LeNet + len-19 full convolution + log.
// Round-15: LDS diet 45.4 KB -> 39.1 KB => 4 blocks/CU (was 3).
//  * s_w2A (5.4 KB, conv2-only) is no longer a separate allocation: it is
//    overlaid into s_pool (floats [3760,5104), past s_log) and staged AFTER
//    the post-conv1 barrier (image region is dead by then). One extra
//    __syncthreads; staging is ~5 items/thread.
//  * __launch_bounds__(256, 4) to pin 4 waves/SIMD.
//  * all math bit-identical to R14 (conv1 MFMA 32x32x16 shift-packed hi/lo,
//    conv2 MFMA 16x16x32 gather, fc1/fc2 lane-paired, merged tail).
// R14 evidence: stall-bound (VALU 46%, MFMA 7.5%, both idle); occupancy is
// the binding resource (LDS-capped at 3 blocks/CU). This round is the A/B.

#define SPB 4            // samples per block (2 pairs, 8 instances)
#define P1H_IN 440       // s_p1h instance stride in half2
#define P1H_IC 144       // channel-pair stride in half2 (3 pairs per inst)

typedef _Float16 f16x2 __attribute__((ext_vector_type(2)));
typedef _Float16 half8 __attribute__((ext_vector_type(8)));
typedef float floatx4 __attribute__((ext_vector_type(4)));
typedef float floatx16 __attribute__((ext_vector_type(16)));

__global__ __launch_bounds__(256, 4) void lenet_fused(
    const float* __restrict__ x,     // [B,2,28,28]
    const float* __restrict__ cw1,   // [6,1,5,5]
    const float* __restrict__ cb1,   // [6]
    const float* __restrict__ cw2,   // [16,6,5,5]
    const float* __restrict__ cb2,   // [16]
    const float* __restrict__ fw1,   // [120,256]
    const float* __restrict__ fb1,   // [120]
    const float* __restrict__ fw2,   // [84,120]
    const float* __restrict__ fb2,   // [84]
    const float* __restrict__ fw3,   // [10,84]
    const float* __restrict__ fb3,   // [10]
    float* __restrict__ out)         // [B,19]
{
    const int tid = threadIdx.x;
    const int b0  = blockIdx.x * SPB;

    __shared__ __align__(16) float s_pool[8 * 784];      // 25088 B (imgHL; reused)
    __shared__ __align__(16) f16x2 s_p1h [8 * P1H_IN];   // 14080 B
    __shared__ __align__(16) float s_w1t [25 * 8];       //   800 B  [k][o]
    __shared__ float s_b1[8];
    __shared__ float s_b2[16];
    // total ~39.1 KB -> 4 blocks/CU

    f16x2* s_imgHL = (f16x2*)s_pool;  // [8 inst][28][28] (hi,lo) pairs
    float* s_p2  = s_pool;           // 2048
    float* s_f1  = s_pool + 2048;    // 960
    float* s_f2  = s_pool + 3008;    // 672
    float* s_log = s_pool + 3680;    // 80
    f16x2* s_w2A = (f16x2*)(s_pool + 3760);  // 1344 f16x2 = [o][kp], conv2 only

    // ---- stage images (hi/lo split, vectorized) + conv1 weights ----
    {
        const float4* xb = (const float4*)(x + (size_t)b0 * 1568);
        float4* sh = (float4*)s_imgHL;
        for (int i = tid; i < 1568; i += 256) {
            float4 q = xb[i];
            union { f16x2 h[4]; float4 v; } u;
            u.h[0].x = (_Float16)q.x; u.h[0].y = (_Float16)(q.x - (float)u.h[0].x);
            u.h[1].x = (_Float16)q.y; u.h[1].y = (_Float16)(q.y - (float)u.h[1].x);
            u.h[2].x = (_Float16)q.z; u.h[2].y = (_Float16)(q.z - (float)u.h[2].x);
            u.h[3].x = (_Float16)q.w; u.h[3].y = (_Float16)(q.w - (float)u.h[3].x);
            sh[i] = u.v;
        }
    }
    for (int i = tid; i < 150; i += 256) {       // cw1 -> [k][o], stride 8
        int o = i / 25, k = i % 25;
        s_w1t[k * 8 + o] = cw1[i];
    }
    if (tid < 8)  s_b1[tid] = (tid < 6) ? cb1[tid] : 0.f;
    if (tid < 16) s_b2[tid] = cb2[tid];
    __syncthreads();

    // ---- conv1 5x5 (1->6) + pool2x2 + relu : MFMA 32x32x16 f16 ----
    // D[32 rows = Y0 (24 valid)][32 cols = (s,ch), 24 valid]; ks outer,
    // xbi inner with 6 independent accs; A-frag = one aligned b128.
    {
        const int lane = tid & 63;
        const int wv   = tid >> 6;
        const int l5   = lane >> 5;
        const int cn   = lane & 31;
        const int s    = cn >> 3;                // x-shift 0..3
        const int ch   = cn & 7;                 // channel 0..7 (<6 valid)
        const int Y0   = cn < 24 ? cn : 23;      // A-row pixel row (clamped)

        // B fragments: B[k' = ks*16 + l5*8 + j][(s,ch)] = w1[ch][ks][kx'-s],
        // kx' = l5*4 + (j>>1), both h-slots identical.
        half8 bfr[5];
#pragma unroll
        for (int ks = 0; ks < 5; ++ks) {
            float w4[4];
#pragma unroll
            for (int q = 0; q < 4; ++q) {
                int kx = l5 * 4 + q - s;
                float wq = 0.f;
                if (ch < 6 && kx >= 0 && kx <= 4)
                    wq = s_w1t[(ks * 5 + kx) * 8 + ch];
                w4[q] = wq;
            }
            half8 b;
            b[0] = (_Float16)w4[0]; b[1] = b[0];
            b[2] = (_Float16)w4[1]; b[3] = b[2];
            b[4] = (_Float16)w4[2]; b[5] = b[4];
            b[6] = (_Float16)w4[3]; b[7] = b[6];
            bfr[ks] = b;
        }
        const float bch = s_b1[ch];
        const int   ybase = Y0 * 28 + l5 * 4;    // half2 units (mod 4 == 0)
        const bool  wrl   = ((s & 1) == 0) && (ch < 6);
        _Float16* p1w = (_Float16*)s_p1h;

        floatx16 zero16 = {0.f,0.f,0.f,0.f, 0.f,0.f,0.f,0.f,
                           0.f,0.f,0.f,0.f, 0.f,0.f,0.f,0.f};

#pragma unroll 1
        for (int ih = 0; ih < 2; ++ih) {
            const int inst = wv + 4 * ih;
            const f16x2* ip = s_imgHL + inst * 784 + ybase;
            const int wb = (inst * P1H_IN + (ch >> 1) * P1H_IC) * 2 + (ch & 1);

            floatx16 acc[6];
#pragma unroll
            for (int xbi = 0; xbi < 6; ++xbi) acc[xbi] = zero16;

#pragma unroll
            for (int ks = 0; ks < 5; ++ks) {
                const f16x2* rp = ip + ks * 28;
#pragma unroll
                for (int xbi = 0; xbi < 6; ++xbi) {
                    half8 a = *(const half8*)(rp + xbi * 4);
                    acc[xbi] = __builtin_amdgcn_mfma_f32_32x32x16_f16(
                        a, bfr[ks], acc[xbi], 0, 0, 0);
                }
            }

            // epilogue: 6 xbi x 8 outputs, all independent.
            // D row = (reg&3) + 8*(reg>>2) + 4*l5 = Y0; col = (s,ch).
#pragma unroll
            for (int xbi = 0; xbi < 6; ++xbi) {
                const int px2 = (xbi * 2 + (s >> 1)) * 2;   // px in halves
#pragma unroll
                for (int d = 0; d < 4; ++d) {
#pragma unroll
                    for (int cp = 0; cp < 2; ++cp) {
                        float vy = fmaxf(acc[xbi][4 * d + 2 * cp],
                                         acc[xbi][4 * d + 2 * cp + 1]); // y-pool
                        float vo = __shfl_xor(vy, 8);              // s^1 col
                        float vp = fmaxf(vy, vo);                  // x-pool
                        float r  = fmaxf(vp + bch, 0.f);
                        int  py  = cp + 4 * d + 2 * l5;
                        if (wrl && py < 12)
                            p1w[wb + py * 24 + px2] = (_Float16)r;
                    }
                }
            }
        }
    }
    __syncthreads();

    // ---- stage conv2 weights into the (now dead) image region ----
    for (int i = tid; i < 16 * 84; i += 256) {   // cw2 -> MFMA A rows [o][kp]
        int o = i / 84, kp = i % 84;
        f16x2 w2;
        if (kp < 75) {
            int icp = kp / 25, r = kp % 25;      // kp = icp*25 + ky*5 + kx
            float we = cw2[o * 150 + (2 * icp    ) * 25 + r];
            float wo = cw2[o * 150 + (2 * icp + 1) * 25 + r];
            w2.x = (_Float16)we; w2.y = (_Float16)wo;
        } else {
            w2.x = (_Float16)0.f; w2.y = (_Float16)0.f;
        }
        s_w2A[i] = w2;
    }
    __syncthreads();

    // ---- conv2 5x5 (6->16) + pool2x2 + relu : MFMA 16x16x32 f16 ----
    {
        const int lane = tid & 63;
        const int wv0  = tid >> 6;               // instance pair: wv0, wv0+4
        const int g    = lane >> 4;              // k-group
        const int cn   = lane & 15;              // A row (=o) / B col (=n%16)

        half8 afr[5];
        const _Float16* wA = (const _Float16*)s_w2A;
#pragma unroll
        for (int ks = 0; ks < 5; ++ks)
            afr[ks] = *(const half8*)(wA + cn * 168 + ks * 32 + g * 8);

        float bias4[4];
#pragma unroll
        for (int r = 0; r < 4; ++r) bias4[r] = s_b2[g * 4 + r];

        const int csb = (cn >> 3) * 12 + (cn & 7);           // + 24*ntl per tile
        const f16x2* pbA = s_p1h + wv0 * P1H_IN + csb;
        const f16x2* pbB = pbA + 4 * P1H_IN;

        floatx4 zero4 = {0.f, 0.f, 0.f, 0.f};
        floatx4 accA[4] = {zero4, zero4, zero4, zero4};
        floatx4 accB[4] = {zero4, zero4, zero4, zero4};

#pragma unroll
        for (int ks = 0; ks < 5; ++ks) {
            int ko[4];
#pragma unroll
            for (int j = 0; j < 4; ++j) {
                int kp = ks * 16 + g * 4 + j;
                kp = kp > 74 ? 74 : kp;          // clamp: garbage meets zero A
                int icp = (int)((unsigned)kp / 25u);
                int r   = kp - icp * 25;
                int ky  = (int)((unsigned)r / 5u);
                int kx  = r - ky * 5;
                ko[j] = icp * P1H_IC + ky * 12 + kx;
            }
#pragma unroll
            for (int ntl = 0; ntl < 4; ++ntl) {
                union { half8 h8; f16x2 h2[4]; } bpA, bpB;
                bpA.h2[0] = pbA[ko[0] + 24 * ntl];
                bpA.h2[1] = pbA[ko[1] + 24 * ntl];
                bpA.h2[2] = pbA[ko[2] + 24 * ntl];
                bpA.h2[3] = pbA[ko[3] + 24 * ntl];
                bpB.h2[0] = pbB[ko[0] + 24 * ntl];
                bpB.h2[1] = pbB[ko[1] + 24 * ntl];
                bpB.h2[2] = pbB[ko[2] + 24 * ntl];
                bpB.h2[3] = pbB[ko[3] + 24 * ntl];
                accA[ntl] = __builtin_amdgcn_mfma_f32_16x16x32_f16(
                    afr[ks], bpA.h8, accA[ntl], 0, 0, 0);
                accB[ntl] = __builtin_amdgcn_mfma_f32_16x16x32_f16(
                    afr[ks], bpB.h8, accB[ntl], 0, 0, 0);
            }
        }

        const int px = (lane & 7) >> 1;
        const bool wrp = (lane & 9) == 0;

#define CONV2_EPI(accv, instv)                                                 \
        {   float* p2o = s_p2 + (instv) * 256 + px;                            \
            _Pragma("unroll")                                                  \
            for (int ntl = 0; ntl < 4; ++ntl) {                                \
                _Pragma("unroll")                                              \
                for (int r = 0; r < 4; ++r) {                                  \
                    float v = accv[ntl][r];                                    \
                    v = fmaxf(v, __shfl_xor(v, 1));                            \
                    v = fmaxf(v, __shfl_xor(v, 8));                            \
                    v = fmaxf(v + bias4[r], 0.f);                              \
                    if (wrp) p2o[(g * 4 + r) * 16 + ntl * 4] = v;              \
                }                                                              \
            }                                                                  \
        }
        CONV2_EPI(accA, wv0);
        CONV2_EPI(accB, wv0 + 4);
#undef CONV2_EPI
    }
    __syncthreads();

    // ---- fc1: 256 -> 120, relu. 240 lanes; lane pair shares weight row,
    //      each lane does 4 instance-dots (fw1 read once per pair) ----
    if (tid < 240) {
        int o  = tid >> 1;                       // 0..119
        int pr = tid & 1;                        // instance group: 4*pr..4*pr+3
        const float4* wr = (const float4*)(fw1 + o * 256);
        const float4* q0 = (const float4*)(s_p2 + (4 * pr    ) * 256);
        const float4* q1 = (const float4*)(s_p2 + (4 * pr + 1) * 256);
        const float4* q2 = (const float4*)(s_p2 + (4 * pr + 2) * 256);
        const float4* q3 = (const float4*)(s_p2 + (4 * pr + 3) * 256);
        float a0 = 0.f, a1 = 0.f, a2 = 0.f, a3 = 0.f;
#pragma unroll 4
        for (int k = 0; k < 64; ++k) {
            float4 w4 = wr[k];
            float4 p;
            p = q0[k]; a0 = fmaf(w4.x,p.x,a0); a0 = fmaf(w4.y,p.y,a0); a0 = fmaf(w4.z,p.z,a0); a0 = fmaf(w4.w,p.w,a0);
            p = q1[k]; a1 = fmaf(w4.x,p.x,a1); a1 = fmaf(w4.y,p.y,a1); a1 = fmaf(w4.z,p.z,a1); a1 = fmaf(w4.w,p.w,a1);
            p = q2[k]; a2 = fmaf(w4.x,p.x,a2); a2 = fmaf(w4.y,p.y,a2); a2 = fmaf(w4.z,p.z,a2); a2 = fmaf(w4.w,p.w,a2);
            p = q3[k]; a3 = fmaf(w4.x,p.x,a3); a3 = fmaf(w4.y,p.y,a3); a3 = fmaf(w4.z,p.z,a3); a3 = fmaf(w4.w,p.w,a3);
        }
        float bb = fb1[o];
        s_f1[(4 * pr    ) * 120 + o] = fmaxf(a0 + bb, 0.f);
        s_f1[(4 * pr + 1) * 120 + o] = fmaxf(a1 + bb, 0.f);
        s_f1[(4 * pr + 2) * 120 + o] = fmaxf(a2 + bb, 0.f);
        s_f1[(4 * pr + 3) * 120 + o] = fmaxf(a3 + bb, 0.f);
    }
    __syncthreads();

    // ---- fc2: 120 -> 84, relu. 168 lanes, same pairing ----
    if (tid < 168) {
        int o  = tid >> 1;                       // 0..83
        int pr = tid & 1;
        const float4* wr = (const float4*)(fw2 + o * 120);
        const float4* q0 = (const float4*)(s_f1 + (4 * pr    ) * 120);
        const float4* q1 = (const float4*)(s_f1 + (4 * pr + 1) * 120);
        const float4* q2 = (const float4*)(s_f1 + (4 * pr + 2) * 120);
        const float4* q3 = (const float4*)(s_f1 + (4 * pr + 3) * 120);
        float a0 = 0.f, a1 = 0.f, a2 = 0.f, a3 = 0.f;
#pragma unroll 5
        for (int k = 0; k < 30; ++k) {
            float4 w4 = wr[k];
            float4 p;
            p = q0[k]; a0 = fmaf(w4.x,p.x,a0); a0 = fmaf(w4.y,p.y,a0); a0 = fmaf(w4.z,p.z,a0); a0 = fmaf(w4.w,p.w,a0);
            p = q1[k]; a1 = fmaf(w4.x,p.x,a1); a1 = fmaf(w4.y,p.y,a1); a1 = fmaf(w4.z,p.z,a1); a1 = fmaf(w4.w,p.w,a1);
            p = q2[k]; a2 = fmaf(w4.x,p.x,a2); a2 = fmaf(w4.y,p.y,a2); a2 = fmaf(w4.z,p.z,a2); a2 = fmaf(w4.w,p.w,a2);
            p = q3[k]; a3 = fmaf(w4.x,p.x,a3); a3 = fmaf(w4.y,p.y,a3); a3 = fmaf(w4.z,p.z,a3); a3 = fmaf(w4.w,p.w,a3);
        }
        float bb = fb2[o];
        s_f2[(4 * pr    ) * 84 + o] = fmaxf(a0 + bb, 0.f);
        s_f2[(4 * pr + 1) * 84 + o] = fmaxf(a1 + bb, 0.f);
        s_f2[(4 * pr + 2) * 84 + o] = fmaxf(a2 + bb, 0.f);
        s_f2[(4 * pr + 3) * 84 + o] = fmaxf(a3 + bb, 0.f);
    }
    __syncthreads();

    // ---- fc3: 84 -> 10. 80 lanes ----
    if (tid < 80) {
        int o    = tid % 10;
        int inst = tid / 10;                     // 0..7
        const float4* wr = (const float4*)(fw3 + o * 84);
        const float4* q0 = (const float4*)(s_f2 + inst * 84);
        float a0 = 0.f;
#pragma unroll
        for (int k = 0; k < 21; ++k) {
            float4 w4 = wr[k];
            float4 p = q0[k];
            a0 = fmaf(w4.x,p.x,a0); a0 = fmaf(w4.y,p.y,a0); a0 = fmaf(w4.z,p.z,a0); a0 = fmaf(w4.w,p.w,a0);
        }
        s_log[inst * 10 + o] = a0 + fb3[o];
    }
    __syncthreads();

    // ---- softmax (in-lane) + full convolution (len 19) + log ----
    if (tid < 19 * SPB) {
        int ls = tid / 19;                       // sample 0..3
        int t  = tid % 19;
        const float* la = &s_log[(ls * 2 + 0) * 10];
        const float* lb = &s_log[(ls * 2 + 1) * 10];
        float pa[10], pb[10];
        float mxa = la[0], mxb = lb[0];
#pragma unroll
        for (int j = 1; j < 10; ++j) { mxa = fmaxf(mxa, la[j]); mxb = fmaxf(mxb, lb[j]); }
        float sa = 0.f, sb = 0.f;
#pragma unroll
        for (int j = 0; j < 10; ++j) {
            pa[j] = __expf(la[j] - mxa); sa += pa[j];
            pb[j] = __expf(lb[j] - mxb); sb += pb[j];
        }
        float inv = 1.f / (sa * sb);
        int jlo = t - 9 > 0 ? t - 9 : 0;
        int jhi = t < 9 ? t : 9;
        float z = 0.f;
        for (int j = jlo; j <= jhi; ++j)
            z += pa[j] * pb[t - j];
        out[(size_t)(b0 + ls) * 19 + t] = __logf(z * inv);
    }
}

extern "C" void kernel_launch(void* const* d_in, const int* in_sizes, int n_in,
                              void* d_out, int out_size, void* d_ws, size_t ws_size,
                              hipStream_t stream) {
    const float* x   = (const float*)d_in[0];
    const float* cw1 = (const float*)d_in[1];
    const float* cb1 = (const float*)d_in[2];
    const float* cw2 = (const float*)d_in[3];
    const float* cb2 = (const float*)d_in[4];
    const float* fw1 = (const float*)d_in[5];
    const float* fb1 = (const float*)d_in[6];
    const float* fw2 = (const float*)d_in[7];
    const float* fb2 = (const float*)d_in[8];
    const float* fw3 = (const float*)d_in[9];
    const float* fb3 = (const float*)d_in[10];
    float* out = (float*)d_out;

    const int B = in_sizes[0] / (2 * 28 * 28);   // 16384

    lenet_fused<<<B / SPB, 256, 0, stream>>>(x, cw1, cb1, cw2, cb2,
                                             fw1, fb1, fw2, fb2, fw3, fb3, out);
}

// Round 6
// 310.157 us; speedup vs baseline: 1.0732x; 1.0732x over previous
//
#include <hip/hip_runtime.h>
#include <math.h>

// Fused dual-LeNet + len-19 full convolution + log.
// Round-16: kill the R15 spill while keeping 4 blocks/CU.
//  * R15 evidence: launch_bounds(256,4) capped regs at 128/lane; conv1's
//    6x16 acc + 20 bfr no longer fit -> VGPR 84->64 + WRITE_SIZE 1.3->53 MB
//    (scratch). Occupancy won 16 us, spills ate the rest.
//  * fix: conv1 xbi accumulators split into 2 chunks of 3 (48 acc regs peak,
//    ~100 total). Same 60 MFMAs, same per-acc accumulation order ->
//    bit-identical numerics. ILP 3 within a chunk + 4 waves/SIMD covers
//    MFMA latency.
//  * everything else identical to R15 (LDS 39.1 KB overlay, conv2 MFMA,
//    lane-paired fc1/fc2, merged tail).

#define SPB 4            // samples per block (2 pairs, 8 instances)
#define P1H_IN 440       // s_p1h instance stride in half2
#define P1H_IC 144       // channel-pair stride in half2 (3 pairs per inst)

typedef _Float16 f16x2 __attribute__((ext_vector_type(2)));
typedef _Float16 half8 __attribute__((ext_vector_type(8)));
typedef float floatx4 __attribute__((ext_vector_type(4)));
typedef float floatx16 __attribute__((ext_vector_type(16)));

__global__ __launch_bounds__(256, 4) void lenet_fused(
    const float* __restrict__ x,     // [B,2,28,28]
    const float* __restrict__ cw1,   // [6,1,5,5]
    const float* __restrict__ cb1,   // [6]
    const float* __restrict__ cw2,   // [16,6,5,5]
    const float* __restrict__ cb2,   // [16]
    const float* __restrict__ fw1,   // [120,256]
    const float* __restrict__ fb1,   // [120]
    const float* __restrict__ fw2,   // [84,120]
    const float* __restrict__ fb2,   // [84]
    const float* __restrict__ fw3,   // [10,84]
    const float* __restrict__ fb3,   // [10]
    float* __restrict__ out)         // [B,19]
{
    const int tid = threadIdx.x;
    const int b0  = blockIdx.x * SPB;

    __shared__ __align__(16) float s_pool[8 * 784];      // 25088 B (imgHL; reused)
    __shared__ __align__(16) f16x2 s_p1h [8 * P1H_IN];   // 14080 B
    __shared__ __align__(16) float s_w1t [25 * 8];       //   800 B  [k][o]
    __shared__ float s_b1[8];
    __shared__ float s_b2[16];
    // total ~39.1 KB -> 4 blocks/CU

    f16x2* s_imgHL = (f16x2*)s_pool;  // [8 inst][28][28] (hi,lo) pairs
    float* s_p2  = s_pool;           // 2048
    float* s_f1  = s_pool + 2048;    // 960
    float* s_f2  = s_pool + 3008;    // 672
    float* s_log = s_pool + 3680;    // 80
    f16x2* s_w2A = (f16x2*)(s_pool + 3760);  // 1344 f16x2 = [o][kp], conv2 only

    // ---- stage images (hi/lo split, vectorized) + conv1 weights ----
    {
        const float4* xb = (const float4*)(x + (size_t)b0 * 1568);
        float4* sh = (float4*)s_imgHL;
        for (int i = tid; i < 1568; i += 256) {
            float4 q = xb[i];
            union { f16x2 h[4]; float4 v; } u;
            u.h[0].x = (_Float16)q.x; u.h[0].y = (_Float16)(q.x - (float)u.h[0].x);
            u.h[1].x = (_Float16)q.y; u.h[1].y = (_Float16)(q.y - (float)u.h[1].x);
            u.h[2].x = (_Float16)q.z; u.h[2].y = (_Float16)(q.z - (float)u.h[2].x);
            u.h[3].x = (_Float16)q.w; u.h[3].y = (_Float16)(q.w - (float)u.h[3].x);
            sh[i] = u.v;
        }
    }
    for (int i = tid; i < 150; i += 256) {       // cw1 -> [k][o], stride 8
        int o = i / 25, k = i % 25;
        s_w1t[k * 8 + o] = cw1[i];
    }
    if (tid < 8)  s_b1[tid] = (tid < 6) ? cb1[tid] : 0.f;
    if (tid < 16) s_b2[tid] = cb2[tid];
    __syncthreads();

    // ---- conv1 5x5 (1->6) + pool2x2 + relu : MFMA 32x32x16 f16 ----
    // D[32 rows = Y0 (24 valid)][32 cols = (s,ch), 24 valid]; xbi chunks of 3
    // (48 acc regs peak), ks inner-outer, 3 independent accs per chunk.
    {
        const int lane = tid & 63;
        const int wv   = tid >> 6;
        const int l5   = lane >> 5;
        const int cn   = lane & 31;
        const int s    = cn >> 3;                // x-shift 0..3
        const int ch   = cn & 7;                 // channel 0..7 (<6 valid)
        const int Y0   = cn < 24 ? cn : 23;      // A-row pixel row (clamped)

        // B fragments: B[k' = ks*16 + l5*8 + j][(s,ch)] = w1[ch][ks][kx'-s],
        // kx' = l5*4 + (j>>1), both h-slots identical.
        half8 bfr[5];
#pragma unroll
        for (int ks = 0; ks < 5; ++ks) {
            float w4[4];
#pragma unroll
            for (int q = 0; q < 4; ++q) {
                int kx = l5 * 4 + q - s;
                float wq = 0.f;
                if (ch < 6 && kx >= 0 && kx <= 4)
                    wq = s_w1t[(ks * 5 + kx) * 8 + ch];
                w4[q] = wq;
            }
            half8 b;
            b[0] = (_Float16)w4[0]; b[1] = b[0];
            b[2] = (_Float16)w4[1]; b[3] = b[2];
            b[4] = (_Float16)w4[2]; b[5] = b[4];
            b[6] = (_Float16)w4[3]; b[7] = b[6];
            bfr[ks] = b;
        }
        const float bch = s_b1[ch];
        const int   ybase = Y0 * 28 + l5 * 4;    // half2 units (mod 4 == 0)
        const bool  wrl   = ((s & 1) == 0) && (ch < 6);
        _Float16* p1w = (_Float16*)s_p1h;

        floatx16 zero16 = {0.f,0.f,0.f,0.f, 0.f,0.f,0.f,0.f,
                           0.f,0.f,0.f,0.f, 0.f,0.f,0.f,0.f};

#pragma unroll 1
        for (int ih = 0; ih < 2; ++ih) {
            const int inst = wv + 4 * ih;
            const f16x2* ip = s_imgHL + inst * 784 + ybase;
            const int wb = (inst * P1H_IN + (ch >> 1) * P1H_IC) * 2 + (ch & 1);

#pragma unroll 1
            for (int xh = 0; xh < 2; ++xh) {
                floatx16 acc[3];
#pragma unroll
                for (int xq = 0; xq < 3; ++xq) acc[xq] = zero16;

#pragma unroll
                for (int ks = 0; ks < 5; ++ks) {
                    const f16x2* rp = ip + ks * 28 + xh * 12;
#pragma unroll
                    for (int xq = 0; xq < 3; ++xq) {
                        half8 a = *(const half8*)(rp + xq * 4);
                        acc[xq] = __builtin_amdgcn_mfma_f32_32x32x16_f16(
                            a, bfr[ks], acc[xq], 0, 0, 0);
                    }
                }

                // epilogue: 3 xq x 8 outputs, all independent.
                // D row = (reg&3) + 8*(reg>>2) + 4*l5 = Y0; col = (s,ch).
#pragma unroll
                for (int xq = 0; xq < 3; ++xq) {
                    const int xbi = xh * 3 + xq;
                    const int px2 = (xbi * 2 + (s >> 1)) * 2;   // px in halves
#pragma unroll
                    for (int d = 0; d < 4; ++d) {
#pragma unroll
                        for (int cp = 0; cp < 2; ++cp) {
                            float vy = fmaxf(acc[xq][4 * d + 2 * cp],
                                             acc[xq][4 * d + 2 * cp + 1]); // y-pool
                            float vo = __shfl_xor(vy, 8);              // s^1 col
                            float vp = fmaxf(vy, vo);                  // x-pool
                            float r  = fmaxf(vp + bch, 0.f);
                            int  py  = cp + 4 * d + 2 * l5;
                            if (wrl && py < 12)
                                p1w[wb + py * 24 + px2] = (_Float16)r;
                        }
                    }
                }
            }
        }
    }
    __syncthreads();

    // ---- stage conv2 weights into the (now dead) image region ----
    for (int i = tid; i < 16 * 84; i += 256) {   // cw2 -> MFMA A rows [o][kp]
        int o = i / 84, kp = i % 84;
        f16x2 w2;
        if (kp < 75) {
            int icp = kp / 25, r = kp % 25;      // kp = icp*25 + ky*5 + kx
            float we = cw2[o * 150 + (2 * icp    ) * 25 + r];
            float wo = cw2[o * 150 + (2 * icp + 1) * 25 + r];
            w2.x = (_Float16)we; w2.y = (_Float16)wo;
        } else {
            w2.x = (_Float16)0.f; w2.y = (_Float16)0.f;
        }
        s_w2A[i] = w2;
    }
    __syncthreads();

    // ---- conv2 5x5 (6->16) + pool2x2 + relu : MFMA 16x16x32 f16 ----
    {
        const int lane = tid & 63;
        const int wv0  = tid >> 6;               // instance pair: wv0, wv0+4
        const int g    = lane >> 4;              // k-group
        const int cn   = lane & 15;              // A row (=o) / B col (=n%16)

        half8 afr[5];
        const _Float16* wA = (const _Float16*)s_w2A;
#pragma unroll
        for (int ks = 0; ks < 5; ++ks)
            afr[ks] = *(const half8*)(wA + cn * 168 + ks * 32 + g * 8);

        float bias4[4];
#pragma unroll
        for (int r = 0; r < 4; ++r) bias4[r] = s_b2[g * 4 + r];

        const int csb = (cn >> 3) * 12 + (cn & 7);           // + 24*ntl per tile
        const f16x2* pbA = s_p1h + wv0 * P1H_IN + csb;
        const f16x2* pbB = pbA + 4 * P1H_IN;

        floatx4 zero4 = {0.f, 0.f, 0.f, 0.f};
        floatx4 accA[4] = {zero4, zero4, zero4, zero4};
        floatx4 accB[4] = {zero4, zero4, zero4, zero4};

#pragma unroll
        for (int ks = 0; ks < 5; ++ks) {
            int ko[4];
#pragma unroll
            for (int j = 0; j < 4; ++j) {
                int kp = ks * 16 + g * 4 + j;
                kp = kp > 74 ? 74 : kp;          // clamp: garbage meets zero A
                int icp = (int)((unsigned)kp / 25u);
                int r   = kp - icp * 25;
                int ky  = (int)((unsigned)r / 5u);
                int kx  = r - ky * 5;
                ko[j] = icp * P1H_IC + ky * 12 + kx;
            }
#pragma unroll
            for (int ntl = 0; ntl < 4; ++ntl) {
                union { half8 h8; f16x2 h2[4]; } bpA, bpB;
                bpA.h2[0] = pbA[ko[0] + 24 * ntl];
                bpA.h2[1] = pbA[ko[1] + 24 * ntl];
                bpA.h2[2] = pbA[ko[2] + 24 * ntl];
                bpA.h2[3] = pbA[ko[3] + 24 * ntl];
                bpB.h2[0] = pbB[ko[0] + 24 * ntl];
                bpB.h2[1] = pbB[ko[1] + 24 * ntl];
                bpB.h2[2] = pbB[ko[2] + 24 * ntl];
                bpB.h2[3] = pbB[ko[3] + 24 * ntl];
                accA[ntl] = __builtin_amdgcn_mfma_f32_16x16x32_f16(
                    afr[ks], bpA.h8, accA[ntl], 0, 0, 0);
                accB[ntl] = __builtin_amdgcn_mfma_f32_16x16x32_f16(
                    afr[ks], bpB.h8, accB[ntl], 0, 0, 0);
            }
        }

        const int px = (lane & 7) >> 1;
        const bool wrp = (lane & 9) == 0;

#define CONV2_EPI(accv, instv)                                                 \
        {   float* p2o = s_p2 + (instv) * 256 + px;                            \
            _Pragma("unroll")                                                  \
            for (int ntl = 0; ntl < 4; ++ntl) {                                \
                _Pragma("unroll")                                              \
                for (int r = 0; r < 4; ++r) {                                  \
                    float v = accv[ntl][r];                                    \
                    v = fmaxf(v, __shfl_xor(v, 1));                            \
                    v = fmaxf(v, __shfl_xor(v, 8));                            \
                    v = fmaxf(v + bias4[r], 0.f);                              \
                    if (wrp) p2o[(g * 4 + r) * 16 + ntl * 4] = v;              \
                }                                                              \
            }                                                                  \
        }
        CONV2_EPI(accA, wv0);
        CONV2_EPI(accB, wv0 + 4);
#undef CONV2_EPI
    }
    __syncthreads();

    // ---- fc1: 256 -> 120, relu. 240 lanes; lane pair shares weight row,
    //      each lane does 4 instance-dots (fw1 read once per pair) ----
    if (tid < 240) {
        int o  = tid >> 1;                       // 0..119
        int pr = tid & 1;                        // instance group: 4*pr..4*pr+3
        const float4* wr = (const float4*)(fw1 + o * 256);
        const float4* q0 = (const float4*)(s_p2 + (4 * pr    ) * 256);
        const float4* q1 = (const float4*)(s_p2 + (4 * pr + 1) * 256);
        const float4* q2 = (const float4*)(s_p2 + (4 * pr + 2) * 256);
        const float4* q3 = (const float4*)(s_p2 + (4 * pr + 3) * 256);
        float a0 = 0.f, a1 = 0.f, a2 = 0.f, a3 = 0.f;
#pragma unroll 4
        for (int k = 0; k < 64; ++k) {
            float4 w4 = wr[k];
            float4 p;
            p = q0[k]; a0 = fmaf(w4.x,p.x,a0); a0 = fmaf(w4.y,p.y,a0); a0 = fmaf(w4.z,p.z,a0); a0 = fmaf(w4.w,p.w,a0);
            p = q1[k]; a1 = fmaf(w4.x,p.x,a1); a1 = fmaf(w4.y,p.y,a1); a1 = fmaf(w4.z,p.z,a1); a1 = fmaf(w4.w,p.w,a1);
            p = q2[k]; a2 = fmaf(w4.x,p.x,a2); a2 = fmaf(w4.y,p.y,a2); a2 = fmaf(w4.z,p.z,a2); a2 = fmaf(w4.w,p.w,a2);
            p = q3[k]; a3 = fmaf(w4.x,p.x,a3); a3 = fmaf(w4.y,p.y,a3); a3 = fmaf(w4.z,p.z,a3); a3 = fmaf(w4.w,p.w,a3);
        }
        float bb = fb1[o];
        s_f1[(4 * pr    ) * 120 + o] = fmaxf(a0 + bb, 0.f);
        s_f1[(4 * pr + 1) * 120 + o] = fmaxf(a1 + bb, 0.f);
        s_f1[(4 * pr + 2) * 120 + o] = fmaxf(a2 + bb, 0.f);
        s_f1[(4 * pr + 3) * 120 + o] = fmaxf(a3 + bb, 0.f);
    }
    __syncthreads();

    // ---- fc2: 120 -> 84, relu. 168 lanes, same pairing ----
    if (tid < 168) {
        int o  = tid >> 1;                       // 0..83
        int pr = tid & 1;
        const float4* wr = (const float4*)(fw2 + o * 120);
        const float4* q0 = (const float4*)(s_f1 + (4 * pr    ) * 120);
        const float4* q1 = (const float4*)(s_f1 + (4 * pr + 1) * 120);
        const float4* q2 = (const float4*)(s_f1 + (4 * pr + 2) * 120);
        const float4* q3 = (const float4*)(s_f1 + (4 * pr + 3) * 120);
        float a0 = 0.f, a1 = 0.f, a2 = 0.f, a3 = 0.f;
#pragma unroll 5
        for (int k = 0; k < 30; ++k) {
            float4 w4 = wr[k];
            float4 p;
            p = q0[k]; a0 = fmaf(w4.x,p.x,a0); a0 = fmaf(w4.y,p.y,a0); a0 = fmaf(w4.z,p.z,a0); a0 = fmaf(w4.w,p.w,a0);
            p = q1[k]; a1 = fmaf(w4.x,p.x,a1); a1 = fmaf(w4.y,p.y,a1); a1 = fmaf(w4.z,p.z,a1); a1 = fmaf(w4.w,p.w,a1);
            p = q2[k]; a2 = fmaf(w4.x,p.x,a2); a2 = fmaf(w4.y,p.y,a2); a2 = fmaf(w4.z,p.z,a2); a2 = fmaf(w4.w,p.w,a2);
            p = q3[k]; a3 = fmaf(w4.x,p.x,a3); a3 = fmaf(w4.z,p.z,a3); a3 = fmaf(w4.y,p.y,a3); a3 = fmaf(w4.w,p.w,a3);
        }
        float bb = fb2[o];
        s_f2[(4 * pr    ) * 84 + o] = fmaxf(a0 + bb, 0.f);
        s_f2[(4 * pr + 1) * 84 + o] = fmaxf(a1 + bb, 0.f);
        s_f2[(4 * pr + 2) * 84 + o] = fmaxf(a2 + bb, 0.f);
        s_f2[(4 * pr + 3) * 84 + o] = fmaxf(a3 + bb, 0.f);
    }
    __syncthreads();

    // ---- fc3: 84 -> 10. 80 lanes ----
    if (tid < 80) {
        int o    = tid % 10;
        int inst = tid / 10;                     // 0..7
        const float4* wr = (const float4*)(fw3 + o * 84);
        const float4* q0 = (const float4*)(s_f2 + inst * 84);
        float a0 = 0.f;
#pragma unroll
        for (int k = 0; k < 21; ++k) {
            float4 w4 = wr[k];
            float4 p = q0[k];
            a0 = fmaf(w4.x,p.x,a0); a0 = fmaf(w4.y,p.y,a0); a0 = fmaf(w4.z,p.z,a0); a0 = fmaf(w4.w,p.w,a0);
        }
        s_log[inst * 10 + o] = a0 + fb3[o];
    }
    __syncthreads();

    // ---- softmax (in-lane) + full convolution (len 19) + log ----
    if (tid < 19 * SPB) {
        int ls = tid / 19;                       // sample 0..3
        int t  = tid % 19;
        const float* la = &s_log[(ls * 2 + 0) * 10];
        const float* lb = &s_log[(ls * 2 + 1) * 10];
        float pa[10], pb[10];
        float mxa = la[0], mxb = lb[0];
#pragma unroll
        for (int j = 1; j < 10; ++j) { mxa = fmaxf(mxa, la[j]); mxb = fmaxf(mxb, lb[j]); }
        float sa = 0.f, sb = 0.f;
#pragma unroll
        for (int j = 0; j < 10; ++j) {
            pa[j] = __expf(la[j] - mxa); sa += pa[j];
            pb[j] = __expf(lb[j] - mxb); sb += pb[j];
        }
        float inv = 1.f / (sa * sb);
        int jlo = t - 9 > 0 ? t - 9 : 0;
        int jhi = t < 9 ? t : 9;
        float z = 0.f;
        for (int j = jlo; j <= jhi; ++j)
            z += pa[j] * pb[t - j];
        out[(size_t)(b0 + ls) * 19 + t] = __logf(z * inv);
    }
}

extern "C" void kernel_launch(void* const* d_in, const int* in_sizes, int n_in,
                              void* d_out, int out_size, void* d_ws, size_t ws_size,
                              hipStream_t stream) {
    const float* x   = (const float*)d_in[0];
    const float* cw1 = (const float*)d_in[1];
    const float* cb1 = (const float*)d_in[2];
    const float* cw2 = (const float*)d_in[3];
    const float* cb2 = (const float*)d_in[4];
    const float* fw1 = (const float*)d_in[5];
    const float* fb1 = (const float*)d_in[6];
    const float* fw2 = (const float*)d_in[7];
    const float* fb2 = (const float*)d_in[8];
    const float* fw3 = (const float*)d_in[9];
    const float* fb3 = (const float*)d_in[10];
    float* out = (float*)d_out;

    const int B = in_sizes[0] / (2 * 28 * 28);   // 16384

    lenet_fused<<<B / SPB, 256, 0, stream>>>(x, cw1, cb1, cw2, cb2,
                                             fw1, fb1, fw2, fb2, fw3, fb3, out);
}

// Round 7
// 296.785 us; speedup vs baseline: 1.1215x; 1.0451x over previous
//
#include <hip/hip_runtime.h>
#include <math.h>

// Fused dual-LeNet + len-19 full convolution + log.
// Round-17: fc1/fc2 move to MFMA, EXACT hi/lo arithmetic (no new quant).
//  * every value v = hi + lo (f16 pair); each orig k gets 4 k'-slots:
//    A:(ahi,alo,ahi,alo) x B:(whi,whi,wlo,wlo) -> sum = a*w to ~2^-21 rel.
//  * weight fragments identical across all blocks -> prep kernel builds
//    MFMA-B-frag tables in d_ws once per launch (fc1: 256 KB, fc2: 96 KB);
//    fc B-operand = one coalesced dwordx4 load, zero VALU.
//  * activations written as packed (hi,lo) u32 by the PRODUCING epilogue
//    (conv2 -> p2h, fc1 -> f1h); A-frag = ds_read_b64 + 2 movs.
//  * fc1: D[inst16][o16], 8 o-tiles, K'=1024: 64 MFMA + ~250 ops/wave
//    (was ~1260 scalar VALU). fc2: 6 o-tiles, K'=512 (K padded 120->128,
//    zeros): <=32 MFMA + ~130 ops. fc3/tail scalar (tiny).
//  * strides padded (p2h 260, f1h 132 u32) for bank spread. LDS 39.1 KB,
//    4 blocks/CU retained. conv1/conv2 identical to R16.

#define SPB 4            // samples per block (2 pairs, 8 instances)
#define P1H_IN 440       // s_p1h instance stride in half2
#define P1H_IC 144       // channel-pair stride in half2 (3 pairs per inst)

typedef _Float16 f16x2 __attribute__((ext_vector_type(2)));
typedef _Float16 half8 __attribute__((ext_vector_type(8)));
typedef float floatx4 __attribute__((ext_vector_type(4)));
typedef float floatx16 __attribute__((ext_vector_type(16)));

// ---- prep: build hi/lo dup-slot MFMA B-frag tables for fc1/fc2 in ws ----
// entry = 16B = one lane's B-frag for (otile, kstep). fc1: [8][32][64] at 0;
// fc2: [6][16][64] at entry 16384. slot pattern per orig k:
// halves = (whi,whi,wlo,wlo) for k0 then k1 (k0 = ks*8 + g*2).
__global__ __launch_bounds__(256) void prep_ws(
    const float* __restrict__ fw1, const float* __restrict__ fw2,
    uint4* __restrict__ ws)
{
    int idx = blockIdx.x * 256 + threadIdx.x;
    if (idx >= 22528) return;
    bool isf2 = idx >= 16384;
    int e  = isf2 ? idx - 16384 : idx;
    int l  = e & 63;
    int ks = (e >> 6) & (isf2 ? 15 : 31);
    int ot = e >> (isf2 ? 10 : 11);
    int cn = l & 15, g = l >> 4;
    int o  = ot * 16 + cn;
    int k0 = ks * 8 + g * 2;
    float w0 = 0.f, w1 = 0.f;
    if (!isf2) {
        if (o < 120) { w0 = fw1[o * 256 + k0]; w1 = fw1[o * 256 + k0 + 1]; }
    } else {
        if (o < 84) {
            if (k0 < 120)     w0 = fw2[o * 120 + k0];
            if (k0 + 1 < 120) w1 = fw2[o * 120 + k0 + 1];
        }
    }
    _Float16 h0 = (_Float16)w0; _Float16 l0 = (_Float16)(w0 - (float)h0);
    _Float16 h1 = (_Float16)w1; _Float16 l1 = (_Float16)(w1 - (float)h1);
    union { uint4 u; _Float16 h[8]; } r;
    r.h[0] = h0; r.h[1] = h0; r.h[2] = l0; r.h[3] = l0;
    r.h[4] = h1; r.h[5] = h1; r.h[6] = l1; r.h[7] = l1;
    ws[idx] = r.u;
}

__global__ __launch_bounds__(256, 4) void lenet_fused(
    const float* __restrict__ x,     // [B,2,28,28]
    const float* __restrict__ cw1,   // [6,1,5,5]
    const float* __restrict__ cb1,   // [6]
    const float* __restrict__ cw2,   // [16,6,5,5]
    const float* __restrict__ cb2,   // [16]
    const float* __restrict__ fb1,   // [120]
    const float* __restrict__ fb2,   // [84]
    const float* __restrict__ fw3,   // [10,84]
    const float* __restrict__ fb3,   // [10]
    const uint4* __restrict__ ws4,   // prep tables
    float* __restrict__ out)         // [B,19]
{
    const int tid = threadIdx.x;
    const int b0  = blockIdx.x * SPB;

    __shared__ __align__(16) float s_pool[8 * 784];      // 25088 B (imgHL; reused)
    __shared__ __align__(16) f16x2 s_p1h [8 * P1H_IN];   // 14080 B
    __shared__ __align__(16) float s_w1t [25 * 8];       //   800 B  [k][o]
    __shared__ float s_b1[8];
    __shared__ float s_b2[16];
    // total ~39.1 KB -> 4 blocks/CU

    f16x2* s_imgHL = (f16x2*)s_pool;          // [8 inst][28][28] (hi,lo) pairs
    uint32_t* s_u32 = (uint32_t*)s_pool;
    // post-conv1 overlay (u32/float units within s_pool):
    //   p2h  [0,2080)    : 8 x 260, (hi,lo) pairs of conv2 out (k = 0..255)
    //   f1h  [2080,3136) : 8 x 132, (hi,lo) pairs of fc1 out (k = 0..127, 120+ = 0)
    //   s_f2 [3136,3808) : 8 x 84 f32
    //   s_log[3808,3888)
    //   s_w2A[3888,5232) : 1344 f16x2, conv2 A rows
    float* s_log = s_pool + 3808;
    f16x2* s_w2A = (f16x2*)(s_pool + 3888);

    // ---- stage images (hi/lo split, vectorized) + conv1 weights ----
    {
        const float4* xb = (const float4*)(x + (size_t)b0 * 1568);
        float4* sh = (float4*)s_imgHL;
        for (int i = tid; i < 1568; i += 256) {
            float4 q = xb[i];
            union { f16x2 h[4]; float4 v; } u;
            u.h[0].x = (_Float16)q.x; u.h[0].y = (_Float16)(q.x - (float)u.h[0].x);
            u.h[1].x = (_Float16)q.y; u.h[1].y = (_Float16)(q.y - (float)u.h[1].x);
            u.h[2].x = (_Float16)q.z; u.h[2].y = (_Float16)(q.z - (float)u.h[2].x);
            u.h[3].x = (_Float16)q.w; u.h[3].y = (_Float16)(q.w - (float)u.h[3].x);
            sh[i] = u.v;
        }
    }
    for (int i = tid; i < 150; i += 256) {       // cw1 -> [k][o], stride 8
        int o = i / 25, k = i % 25;
        s_w1t[k * 8 + o] = cw1[i];
    }
    if (tid < 8)  s_b1[tid] = (tid < 6) ? cb1[tid] : 0.f;
    if (tid < 16) s_b2[tid] = cb2[tid];
    __syncthreads();

    // ---- conv1 5x5 (1->6) + pool2x2 + relu : MFMA 32x32x16 f16 ----
    // (identical to R16: xbi chunks of 3, no spill at 128-reg cap)
    {
        const int lane = tid & 63;
        const int wv   = tid >> 6;
        const int l5   = lane >> 5;
        const int cn   = lane & 31;
        const int s    = cn >> 3;                // x-shift 0..3
        const int ch   = cn & 7;                 // channel 0..7 (<6 valid)
        const int Y0   = cn < 24 ? cn : 23;      // A-row pixel row (clamped)

        half8 bfr[5];
#pragma unroll
        for (int ks = 0; ks < 5; ++ks) {
            float w4[4];
#pragma unroll
            for (int q = 0; q < 4; ++q) {
                int kx = l5 * 4 + q - s;
                float wq = 0.f;
                if (ch < 6 && kx >= 0 && kx <= 4)
                    wq = s_w1t[(ks * 5 + kx) * 8 + ch];
                w4[q] = wq;
            }
            half8 b;
            b[0] = (_Float16)w4[0]; b[1] = b[0];
            b[2] = (_Float16)w4[1]; b[3] = b[2];
            b[4] = (_Float16)w4[2]; b[5] = b[4];
            b[6] = (_Float16)w4[3]; b[7] = b[6];
            bfr[ks] = b;
        }
        const float bch = s_b1[ch];
        const int   ybase = Y0 * 28 + l5 * 4;    // half2 units (mod 4 == 0)
        const bool  wrl   = ((s & 1) == 0) && (ch < 6);
        _Float16* p1w = (_Float16*)s_p1h;

        floatx16 zero16 = {0.f,0.f,0.f,0.f, 0.f,0.f,0.f,0.f,
                           0.f,0.f,0.f,0.f, 0.f,0.f,0.f,0.f};

#pragma unroll 1
        for (int ih = 0; ih < 2; ++ih) {
            const int inst = wv + 4 * ih;
            const f16x2* ip = s_imgHL + inst * 784 + ybase;
            const int wb = (inst * P1H_IN + (ch >> 1) * P1H_IC) * 2 + (ch & 1);

#pragma unroll 1
            for (int xh = 0; xh < 2; ++xh) {
                floatx16 acc[3];
#pragma unroll
                for (int xq = 0; xq < 3; ++xq) acc[xq] = zero16;

#pragma unroll
                for (int ks = 0; ks < 5; ++ks) {
                    const f16x2* rp = ip + ks * 28 + xh * 12;
#pragma unroll
                    for (int xq = 0; xq < 3; ++xq) {
                        half8 a = *(const half8*)(rp + xq * 4);
                        acc[xq] = __builtin_amdgcn_mfma_f32_32x32x16_f16(
                            a, bfr[ks], acc[xq], 0, 0, 0);
                    }
                }

#pragma unroll
                for (int xq = 0; xq < 3; ++xq) {
                    const int xbi = xh * 3 + xq;
                    const int px2 = (xbi * 2 + (s >> 1)) * 2;   // px in halves
#pragma unroll
                    for (int d = 0; d < 4; ++d) {
#pragma unroll
                        for (int cp = 0; cp < 2; ++cp) {
                            float vy = fmaxf(acc[xq][4 * d + 2 * cp],
                                             acc[xq][4 * d + 2 * cp + 1]); // y-pool
                            float vo = __shfl_xor(vy, 8);              // s^1 col
                            float vp = fmaxf(vy, vo);                  // x-pool
                            float r  = fmaxf(vp + bch, 0.f);
                            int  py  = cp + 4 * d + 2 * l5;
                            if (wrl && py < 12)
                                p1w[wb + py * 24 + px2] = (_Float16)r;
                        }
                    }
                }
            }
        }
    }
    __syncthreads();

    // ---- stage conv2 weights into the (now dead) image region ----
    for (int i = tid; i < 16 * 84; i += 256) {   // cw2 -> MFMA A rows [o][kp]
        int o = i / 84, kp = i % 84;
        f16x2 w2;
        if (kp < 75) {
            int icp = kp / 25, r = kp % 25;      // kp = icp*25 + ky*5 + kx
            float we = cw2[o * 150 + (2 * icp    ) * 25 + r];
            float wo = cw2[o * 150 + (2 * icp + 1) * 25 + r];
            w2.x = (_Float16)we; w2.y = (_Float16)wo;
        } else {
            w2.x = (_Float16)0.f; w2.y = (_Float16)0.f;
        }
        s_w2A[i] = w2;
    }
    __syncthreads();

    // ---- conv2 5x5 (6->16) + pool2x2 + relu : MFMA 16x16x32 f16 ----
    // epilogue now writes (hi,lo) f16 pairs into p2h (fc1's A-operand).
    {
        const int lane = tid & 63;
        const int wv0  = tid >> 6;               // instance pair: wv0, wv0+4
        const int g    = lane >> 4;              // k-group
        const int cn   = lane & 15;              // A row (=o) / B col (=n%16)

        half8 afr[5];
        const _Float16* wA = (const _Float16*)s_w2A;
#pragma unroll
        for (int ks = 0; ks < 5; ++ks)
            afr[ks] = *(const half8*)(wA + cn * 168 + ks * 32 + g * 8);

        float bias4[4];
#pragma unroll
        for (int r = 0; r < 4; ++r) bias4[r] = s_b2[g * 4 + r];

        const int csb = (cn >> 3) * 12 + (cn & 7);           // + 24*ntl per tile
        const f16x2* pbA = s_p1h + wv0 * P1H_IN + csb;
        const f16x2* pbB = pbA + 4 * P1H_IN;

        floatx4 zero4 = {0.f, 0.f, 0.f, 0.f};
        floatx4 accA[4] = {zero4, zero4, zero4, zero4};
        floatx4 accB[4] = {zero4, zero4, zero4, zero4};

#pragma unroll
        for (int ks = 0; ks < 5; ++ks) {
            int ko[4];
#pragma unroll
            for (int j = 0; j < 4; ++j) {
                int kp = ks * 16 + g * 4 + j;
                kp = kp > 74 ? 74 : kp;          // clamp: garbage meets zero A
                int icp = (int)((unsigned)kp / 25u);
                int r   = kp - icp * 25;
                int ky  = (int)((unsigned)r / 5u);
                int kx  = r - ky * 5;
                ko[j] = icp * P1H_IC + ky * 12 + kx;
            }
#pragma unroll
            for (int ntl = 0; ntl < 4; ++ntl) {
                union { half8 h8; f16x2 h2[4]; } bpA, bpB;
                bpA.h2[0] = pbA[ko[0] + 24 * ntl];
                bpA.h2[1] = pbA[ko[1] + 24 * ntl];
                bpA.h2[2] = pbA[ko[2] + 24 * ntl];
                bpA.h2[3] = pbA[ko[3] + 24 * ntl];
                bpB.h2[0] = pbB[ko[0] + 24 * ntl];
                bpB.h2[1] = pbB[ko[1] + 24 * ntl];
                bpB.h2[2] = pbB[ko[2] + 24 * ntl];
                bpB.h2[3] = pbB[ko[3] + 24 * ntl];
                accA[ntl] = __builtin_amdgcn_mfma_f32_16x16x32_f16(
                    afr[ks], bpA.h8, accA[ntl], 0, 0, 0);
                accB[ntl] = __builtin_amdgcn_mfma_f32_16x16x32_f16(
                    afr[ks], bpB.h8, accB[ntl], 0, 0, 0);
            }
        }

        const int px = (lane & 7) >> 1;
        const bool wrp = (lane & 9) == 0;

#define CONV2_EPI(accv, instv)                                                 \
        {   uint32_t* p2o = s_u32 + (instv) * 260 + px;                        \
            _Pragma("unroll")                                                  \
            for (int ntl = 0; ntl < 4; ++ntl) {                                \
                _Pragma("unroll")                                              \
                for (int r = 0; r < 4; ++r) {                                  \
                    float v = accv[ntl][r];                                    \
                    v = fmaxf(v, __shfl_xor(v, 1));                            \
                    v = fmaxf(v, __shfl_xor(v, 8));                            \
                    v = fmaxf(v + bias4[r], 0.f);                              \
                    _Float16 hi = (_Float16)v;                                 \
                    _Float16 lo = (_Float16)(v - (float)hi);                   \
                    f16x2 pr; pr.x = hi; pr.y = lo;                            \
                    if (wrp) p2o[(g * 4 + r) * 16 + ntl * 4] =                 \
                        __builtin_bit_cast(uint32_t, pr);                      \
                }                                                              \
            }                                                                  \
        }
        CONV2_EPI(accA, wv0);
        CONV2_EPI(accB, wv0 + 4);
#undef CONV2_EPI
    }
    __syncthreads();

    // ---- fc1: 256 -> 120, relu : MFMA 16x16x32, exact hi/lo ----
    // D[inst 16][o 16] per o-tile; wave wv owns tiles {wv, wv+4}.
    // A = p2h acts (shared), B = ws table (coalesced dwordx4, zero VALU).
    {
        const int lane = tid & 63, wv = tid >> 6;
        const int cn = lane & 15, g4 = lane >> 4;
        const uint2* apb = (const uint2*)(s_u32 + (cn & 7) * 260);
        const uint4* bw0 = ws4 + (size_t)wv * 2048 + lane;
        const uint4* bw1 = ws4 + (size_t)(wv + 4) * 2048 + lane;
        floatx4 acc0 = {0.f,0.f,0.f,0.f}, acc1 = {0.f,0.f,0.f,0.f};
#pragma unroll 4
        for (int ks = 0; ks < 32; ++ks) {
            uint2 a2 = apb[ks * 4 + g4];         // pairs (k0,k1), k0 = ks*8+g4*2
            union { half8 h; uint32_t u[4]; } af;
            af.u[0] = a2.x; af.u[1] = a2.x; af.u[2] = a2.y; af.u[3] = a2.y;
            union { half8 h; uint4 u; } b0, b1;
            b0.u = bw0[ks * 64]; b1.u = bw1[ks * 64];
            acc0 = __builtin_amdgcn_mfma_f32_16x16x32_f16(af.h, b0.h, acc0, 0,0,0);
            acc1 = __builtin_amdgcn_mfma_f32_16x16x32_f16(af.h, b1.h, acc1, 0,0,0);
        }
        // store (hi,lo) pairs; o>=120 -> 0 (zero-pads fc2's K)
#pragma unroll
        for (int t = 0; t < 2; ++t) {
            int o = (wv + 4 * t) * 16 + cn;
            floatx4 a = t ? acc1 : acc0;
            float bias = (o < 120) ? fb1[o] : 0.f;
            if (g4 < 2) {
#pragma unroll
                for (int r = 0; r < 4; ++r) {
                    int inst = g4 * 4 + r;
                    float v = fmaxf(a[r] + bias, 0.f);
                    if (o >= 120) v = 0.f;
                    _Float16 hi = (_Float16)v;
                    _Float16 lo = (_Float16)(v - (float)hi);
                    f16x2 pr; pr.x = hi; pr.y = lo;
                    s_u32[2080 + inst * 132 + o] = __builtin_bit_cast(uint32_t, pr);
                }
            }
        }
    }
    __syncthreads();

    // ---- fc2: 120 -> 84, relu : MFMA 16x16x32, exact hi/lo ----
    // 6 o-tiles: waves 0,1 own {w, w+4}; waves 2,3 own {w}.
    {
        const int lane = tid & 63, wv = tid >> 6;
        const int cn = lane & 15, g4 = lane >> 4;
        const uint2* apb = (const uint2*)(s_u32 + 2080 + (cn & 7) * 132);
        const uint4* wsf2 = ws4 + 16384;
        const uint4* bw0 = wsf2 + (size_t)wv * 1024 + lane;
        const uint4* bw1 = wsf2 + (size_t)(wv + 4) * 1024 + lane;
        const bool has1 = wv < 2;
        floatx4 acc0 = {0.f,0.f,0.f,0.f}, acc1 = {0.f,0.f,0.f,0.f};
#pragma unroll 4
        for (int ks = 0; ks < 16; ++ks) {
            uint2 a2 = apb[ks * 4 + g4];
            union { half8 h; uint32_t u[4]; } af;
            af.u[0] = a2.x; af.u[1] = a2.x; af.u[2] = a2.y; af.u[3] = a2.y;
            union { half8 h; uint4 u; } b0;
            b0.u = bw0[ks * 64];
            acc0 = __builtin_amdgcn_mfma_f32_16x16x32_f16(af.h, b0.h, acc0, 0,0,0);
            if (has1) {
                union { half8 h; uint4 u; } b1;
                b1.u = bw1[ks * 64];
                acc1 = __builtin_amdgcn_mfma_f32_16x16x32_f16(af.h, b1.h, acc1, 0,0,0);
            }
        }
        float* s_f2 = (float*)(s_u32 + 3136);
#pragma unroll
        for (int t = 0; t < 2; ++t) {
            if (t && !has1) break;
            int o = (wv + 4 * t) * 16 + cn;
            floatx4 a = t ? acc1 : acc0;
            if (o < 84 && g4 < 2) {
                float bias = fb2[o];
#pragma unroll
                for (int r = 0; r < 4; ++r) {
                    int inst = g4 * 4 + r;
                    s_f2[inst * 84 + o] = fmaxf(a[r] + bias, 0.f);
                }
            }
        }
    }
    __syncthreads();

    // ---- fc3: 84 -> 10. 80 lanes ----
    if (tid < 80) {
        int o    = tid % 10;
        int inst = tid / 10;                     // 0..7
        const float4* wr = (const float4*)(fw3 + o * 84);
        const float4* q0 = (const float4*)(s_pool + 3136 + inst * 84);
        float a0 = 0.f;
#pragma unroll
        for (int k = 0; k < 21; ++k) {
            float4 w4 = wr[k];
            float4 p = q0[k];
            a0 = fmaf(w4.x,p.x,a0); a0 = fmaf(w4.y,p.y,a0); a0 = fmaf(w4.z,p.z,a0); a0 = fmaf(w4.w,p.w,a0);
        }
        s_log[inst * 10 + o] = a0 + fb3[o];
    }
    __syncthreads();

    // ---- softmax (in-lane) + full convolution (len 19) + log ----
    if (tid < 19 * SPB) {
        int ls = tid / 19;                       // sample 0..3
        int t  = tid % 19;
        const float* la = &s_log[(ls * 2 + 0) * 10];
        const float* lb = &s_log[(ls * 2 + 1) * 10];
        float pa[10], pb[10];
        float mxa = la[0], mxb = lb[0];
#pragma unroll
        for (int j = 1; j < 10; ++j) { mxa = fmaxf(mxa, la[j]); mxb = fmaxf(mxb, lb[j]); }
        float sa = 0.f, sb = 0.f;
#pragma unroll
        for (int j = 0; j < 10; ++j) {
            pa[j] = __expf(la[j] - mxa); sa += pa[j];
            pb[j] = __expf(lb[j] - mxb); sb += pb[j];
        }
        float inv = 1.f / (sa * sb);
        int jlo = t - 9 > 0 ? t - 9 : 0;
        int jhi = t < 9 ? t : 9;
        float z = 0.f;
        for (int j = jlo; j <= jhi; ++j)
            z += pa[j] * pb[t - j];
        out[(size_t)(b0 + ls) * 19 + t] = __logf(z * inv);
    }
}

extern "C" void kernel_launch(void* const* d_in, const int* in_sizes, int n_in,
                              void* d_out, int out_size, void* d_ws, size_t ws_size,
                              hipStream_t stream) {
    const float* x   = (const float*)d_in[0];
    const float* cw1 = (const float*)d_in[1];
    const float* cb1 = (const float*)d_in[2];
    const float* cw2 = (const float*)d_in[3];
    const float* cb2 = (const float*)d_in[4];
    const float* fw1 = (const float*)d_in[5];
    const float* fb1 = (const float*)d_in[6];
    const float* fw2 = (const float*)d_in[7];
    const float* fb2 = (const float*)d_in[8];
    const float* fw3 = (const float*)d_in[9];
    const float* fb3 = (const float*)d_in[10];
    float* out = (float*)d_out;
    uint4* ws4 = (uint4*)d_ws;                   // 352 KB used

    const int B = in_sizes[0] / (2 * 28 * 28);   // 16384

    prep_ws<<<88, 256, 0, stream>>>(fw1, fw2, ws4);
    lenet_fused<<<B / SPB, 256, 0, stream>>>(x, cw1, cb1, cw2, cb2,
                                             fb1, fb2, fw3, fb3, ws4, out);
}

// Round 8
// 277.112 us; speedup vs baseline: 1.2011x; 1.0710x over previous
//
#include <hip/hip_runtime.h>
#include <math.h>

// Fused dual-LeNet + len-19 full convolution + log.
// Round-18: occupancy 4 -> 5 blocks/CU via LDS diet (40.4 -> 29.6 KB).
//  * pair-at-a-time image staging: stage 4 inst (12.5 KB), conv1, barrier,
//    stage next 4 into same region (conv1 already 2-pass over ih).
//  * prep_ws now also builds conv1 B-frags, conv2 A-frags and conv2 gather
//    LDS-offset tables (block-invariant, lane-indexed): read back as 5
//    coalesced L2-hit dwordx4 per phase. Removes s_w1t + s_w2A staging,
//    one barrier, ~300 VALU/lane of frag building + conv2 div/mod chains.
//  * LDS = 15552 (pool) + 14080 (p1h) = 29.6 KB -> 5 blocks/CU,
//    __launch_bounds__(256,5). VGPR cap ~96 > measured 64 -> no spill
//    expected (WRITE_SIZE is the tripwire).
//  * all arithmetic bit-identical to R17 (absmax 0.03125 expected).

#define SPB 4            // samples per block (2 pairs, 8 instances)
#define P1H_IN 440       // s_p1h instance stride in half2
#define P1H_IC 144       // channel-pair stride in half2 (3 pairs per inst)

typedef _Float16 f16x2 __attribute__((ext_vector_type(2)));
typedef _Float16 half8 __attribute__((ext_vector_type(8)));
typedef float floatx4 __attribute__((ext_vector_type(4)));
typedef float floatx16 __attribute__((ext_vector_type(16)));

// ws layout (uint4 entries):
//  [0,16384)      fc1 B-frags [8 otile][32 ks][64 lane]  (hi/lo dup-slot)
//  [16384,22528)  fc2 B-frags [6 otile][16 ks][64 lane]
//  [22528,22848)  conv1 B-frags [5 ks][64 lane]
//  [22848,23168)  conv2 A-frags [5 ks][64 lane]
//  [23168,23488)  conv2 B-gather LDS offsets [5 ks][64 lane] (int4)
#define WS_C1B 22528
#define WS_C2A 22848
#define WS_C2K 23168
#define WS_TOT 23488

__global__ __launch_bounds__(256) void prep_ws(
    const float* __restrict__ fw1, const float* __restrict__ fw2,
    const float* __restrict__ cw1, const float* __restrict__ cw2,
    uint4* __restrict__ ws)
{
    int idx = blockIdx.x * 256 + threadIdx.x;
    if (idx >= WS_TOT) return;
    if (idx < WS_C1B) {
        // fc1/fc2 hi/lo dup-slot B-frags (identical to R17)
        bool isf2 = idx >= 16384;
        int e  = isf2 ? idx - 16384 : idx;
        int l  = e & 63;
        int ks = (e >> 6) & (isf2 ? 15 : 31);
        int ot = e >> (isf2 ? 10 : 11);
        int cn = l & 15, g = l >> 4;
        int o  = ot * 16 + cn;
        int k0 = ks * 8 + g * 2;
        float w0 = 0.f, w1 = 0.f;
        if (!isf2) {
            if (o < 120) { w0 = fw1[o * 256 + k0]; w1 = fw1[o * 256 + k0 + 1]; }
        } else {
            if (o < 84) {
                if (k0 < 120)     w0 = fw2[o * 120 + k0];
                if (k0 + 1 < 120) w1 = fw2[o * 120 + k0 + 1];
            }
        }
        _Float16 h0 = (_Float16)w0; _Float16 l0 = (_Float16)(w0 - (float)h0);
        _Float16 h1 = (_Float16)w1; _Float16 l1 = (_Float16)(w1 - (float)h1);
        union { uint4 u; _Float16 h[8]; } r;
        r.h[0] = h0; r.h[1] = h0; r.h[2] = l0; r.h[3] = l0;
        r.h[4] = h1; r.h[5] = h1; r.h[6] = l1; r.h[7] = l1;
        ws[idx] = r.u;
    } else if (idx < WS_C2A) {
        // conv1 B-frags: shift-packed (4 shifts x 6 ch), dup halves
        int e = idx - WS_C1B; int l = e & 63; int ks = e >> 6;
        int l5 = l >> 5, cn = l & 31, s = cn >> 3, ch = cn & 7;
        union { uint4 u; _Float16 h[8]; } r;
        for (int q = 0; q < 4; ++q) {
            int kx = l5 * 4 + q - s;
            float wq = (ch < 6 && kx >= 0 && kx <= 4)
                     ? cw1[ch * 25 + ks * 5 + kx] : 0.f;
            r.h[2 * q]     = (_Float16)wq;
            r.h[2 * q + 1] = r.h[2 * q];
        }
        ws[idx] = r.u;
    } else if (idx < WS_C2K) {
        // conv2 A-frags: wA[cn][ks*32+g*8 .. +7], channel-pair interleave
        int e = idx - WS_C2A; int l = e & 63; int ks = e >> 6;
        int cn = l & 15, g = l >> 4;
        union { uint4 u; _Float16 h[8]; } r;
        for (int j = 0; j < 8; ++j) {
            int hidx = ks * 32 + g * 8 + j;
            int kp = hidx >> 1, el = hidx & 1;
            float w = 0.f;
            if (kp < 75) {
                int icp = kp / 25, rr = kp % 25;
                w = cw2[cn * 150 + (2 * icp + el) * 25 + rr];
            }
            r.h[j] = (_Float16)w;
        }
        ws[idx] = r.u;
    } else {
        // conv2 B-gather LDS offsets (half2 units), clamped at kp=74
        int e = idx - WS_C2K; int l = e & 63; int ks = e >> 6;
        int g = l >> 4;
        union { uint4 u; int i[4]; } r;
        for (int j = 0; j < 4; ++j) {
            int kp = ks * 16 + g * 4 + j;
            kp = kp > 74 ? 74 : kp;
            int icp = kp / 25, rr = kp % 25, ky = rr / 5, kx = rr % 5;
            r.i[j] = icp * P1H_IC + ky * 12 + kx;
        }
        ws[idx] = r.u;
    }
}

__global__ __launch_bounds__(256, 5) void lenet_fused(
    const float* __restrict__ x,     // [B,2,28,28]
    const float* __restrict__ cb1,   // [6]
    const float* __restrict__ cb2,   // [16]
    const float* __restrict__ fb1,   // [120]
    const float* __restrict__ fb2,   // [84]
    const float* __restrict__ fw3,   // [10,84]
    const float* __restrict__ fb3,   // [10]
    const uint4* __restrict__ ws4,   // prep tables
    float* __restrict__ out)         // [B,19]
{
    const int tid = threadIdx.x;
    const int b0  = blockIdx.x * SPB;

    __shared__ __align__(16) float s_pool[3888];         // 15552 B
    __shared__ __align__(16) f16x2 s_p1h [8 * P1H_IN];   // 14080 B
    // total ~29.6 KB -> 5 blocks/CU

    f16x2* s_imgHL = (f16x2*)s_pool;          // pair-local [4 inst][784]
    uint32_t* s_u32 = (uint32_t*)s_pool;
    // post-conv1 overlay (u32/float units):
    //   p2h  [0,2080)    : 8 x 260 (hi,lo) pairs of conv2 out
    //   f1h  [2080,3136) : 8 x 132 (hi,lo) pairs of fc1 out
    //   s_f2 [3136,3808) : 8 x 84 f32
    //   s_log[3808,3888)
    float* s_log = s_pool + 3808;

    const int lane = tid & 63;
    const int wv   = tid >> 6;

    // ---- conv1 5x5 (1->6) + pool2x2 + relu : MFMA 32x32x16, pair-at-a-time ----
    {
        const int l5   = lane >> 5;
        const int cn   = lane & 31;
        const int s    = cn >> 3;                // x-shift 0..3
        const int ch   = cn & 7;                 // channel 0..7 (<6 valid)
        const int Y0   = cn < 24 ? cn : 23;      // A-row pixel row (clamped)

        half8 bfr[5];
#pragma unroll
        for (int ks = 0; ks < 5; ++ks) {
            union { uint4 u; half8 h; } t;
            t.u = ws4[WS_C1B + ks * 64 + lane];
            bfr[ks] = t.h;
        }
        const float bch = (ch < 6) ? cb1[ch] : 0.f;
        const int   ybase = Y0 * 28 + l5 * 4;    // half2 units (mod 4 == 0)
        const bool  wrl   = ((s & 1) == 0) && (ch < 6);
        _Float16* p1w = (_Float16*)s_p1h;

        floatx16 zero16 = {0.f,0.f,0.f,0.f, 0.f,0.f,0.f,0.f,
                           0.f,0.f,0.f,0.f, 0.f,0.f,0.f,0.f};

#pragma unroll 1
        for (int p = 0; p < 2; ++p) {
            // stage pair p (4 instances, hi/lo split, vectorized)
            {
                const float4* xb = (const float4*)(x + (size_t)b0 * 1568) + p * 784;
                float4* sh = (float4*)s_imgHL;
                for (int i = tid; i < 784; i += 256) {
                    float4 q = xb[i];
                    union { f16x2 h[4]; float4 v; } u;
                    u.h[0].x = (_Float16)q.x; u.h[0].y = (_Float16)(q.x - (float)u.h[0].x);
                    u.h[1].x = (_Float16)q.y; u.h[1].y = (_Float16)(q.y - (float)u.h[1].x);
                    u.h[2].x = (_Float16)q.z; u.h[2].y = (_Float16)(q.z - (float)u.h[2].x);
                    u.h[3].x = (_Float16)q.w; u.h[3].y = (_Float16)(q.w - (float)u.h[3].x);
                    sh[i] = u.v;
                }
            }
            __syncthreads();

            const int inst = wv + 4 * p;
            const f16x2* ip = s_imgHL + wv * 784 + ybase;
            const int wb = (inst * P1H_IN + (ch >> 1) * P1H_IC) * 2 + (ch & 1);

#pragma unroll 1
            for (int xh = 0; xh < 2; ++xh) {
                floatx16 acc[3];
#pragma unroll
                for (int xq = 0; xq < 3; ++xq) acc[xq] = zero16;

#pragma unroll
                for (int ks = 0; ks < 5; ++ks) {
                    const f16x2* rp = ip + ks * 28 + xh * 12;
#pragma unroll
                    for (int xq = 0; xq < 3; ++xq) {
                        half8 a = *(const half8*)(rp + xq * 4);
                        acc[xq] = __builtin_amdgcn_mfma_f32_32x32x16_f16(
                            a, bfr[ks], acc[xq], 0, 0, 0);
                    }
                }

                // epilogue: 3 xq x 8 outputs, all independent.
                // D row = (reg&3) + 8*(reg>>2) + 4*l5 = Y0; col = (s,ch).
#pragma unroll
                for (int xq = 0; xq < 3; ++xq) {
                    const int xbi = xh * 3 + xq;
                    const int px2 = (xbi * 2 + (s >> 1)) * 2;   // px in halves
#pragma unroll
                    for (int d = 0; d < 4; ++d) {
#pragma unroll
                        for (int cp = 0; cp < 2; ++cp) {
                            float vy = fmaxf(acc[xq][4 * d + 2 * cp],
                                             acc[xq][4 * d + 2 * cp + 1]); // y-pool
                            float vo = __shfl_xor(vy, 8);              // s^1 col
                            float vp = fmaxf(vy, vo);                  // x-pool
                            float r  = fmaxf(vp + bch, 0.f);
                            int  py  = cp + 4 * d + 2 * l5;
                            if (wrl && py < 12)
                                p1w[wb + py * 24 + px2] = (_Float16)r;
                        }
                    }
                }
            }
            __syncthreads();
        }
    }

    // ---- conv2 5x5 (6->16) + pool2x2 + relu : MFMA 16x16x32 f16 ----
    // A-frags + gather offsets from ws tables (L2-hit coalesced loads).
    {
        const int g  = lane >> 4;                // k-group
        const int cn = lane & 15;                // A row (=o) / B col (=n%16)

        half8 afr[5];
        int4  kot[5];
#pragma unroll
        for (int ks = 0; ks < 5; ++ks) {
            union { uint4 u; half8 h; } t;
            t.u = ws4[WS_C2A + ks * 64 + lane];
            afr[ks] = t.h;
            union { uint4 u; int4 i; } k;
            k.u = ws4[WS_C2K + ks * 64 + lane];
            kot[ks] = k.i;
        }

        float bias4[4];
#pragma unroll
        for (int r = 0; r < 4; ++r) bias4[r] = cb2[g * 4 + r];

        const int csb = (cn >> 3) * 12 + (cn & 7);           // + 24*ntl per tile
        const f16x2* pbA = s_p1h + wv * P1H_IN + csb;
        const f16x2* pbB = pbA + 4 * P1H_IN;

        floatx4 zero4 = {0.f, 0.f, 0.f, 0.f};
        floatx4 accA[4] = {zero4, zero4, zero4, zero4};
        floatx4 accB[4] = {zero4, zero4, zero4, zero4};

#pragma unroll
        for (int ks = 0; ks < 5; ++ks) {
            const int k0 = kot[ks].x, k1 = kot[ks].y,
                      k2 = kot[ks].z, k3 = kot[ks].w;
#pragma unroll
            for (int ntl = 0; ntl < 4; ++ntl) {
                union { half8 h8; f16x2 h2[4]; } bpA, bpB;
                bpA.h2[0] = pbA[k0 + 24 * ntl];
                bpA.h2[1] = pbA[k1 + 24 * ntl];
                bpA.h2[2] = pbA[k2 + 24 * ntl];
                bpA.h2[3] = pbA[k3 + 24 * ntl];
                bpB.h2[0] = pbB[k0 + 24 * ntl];
                bpB.h2[1] = pbB[k1 + 24 * ntl];
                bpB.h2[2] = pbB[k2 + 24 * ntl];
                bpB.h2[3] = pbB[k3 + 24 * ntl];
                accA[ntl] = __builtin_amdgcn_mfma_f32_16x16x32_f16(
                    afr[ks], bpA.h8, accA[ntl], 0, 0, 0);
                accB[ntl] = __builtin_amdgcn_mfma_f32_16x16x32_f16(
                    afr[ks], bpB.h8, accB[ntl], 0, 0, 0);
            }
        }

        const int px = (lane & 7) >> 1;
        const bool wrp = (lane & 9) == 0;

#define CONV2_EPI(accv, instv)                                                 \
        {   uint32_t* p2o = s_u32 + (instv) * 260 + px;                        \
            _Pragma("unroll")                                                  \
            for (int ntl = 0; ntl < 4; ++ntl) {                                \
                _Pragma("unroll")                                              \
                for (int r = 0; r < 4; ++r) {                                  \
                    float v = accv[ntl][r];                                    \
                    v = fmaxf(v, __shfl_xor(v, 1));                            \
                    v = fmaxf(v, __shfl_xor(v, 8));                            \
                    v = fmaxf(v + bias4[r], 0.f);                              \
                    _Float16 hi = (_Float16)v;                                 \
                    _Float16 lo = (_Float16)(v - (float)hi);                   \
                    f16x2 pr; pr.x = hi; pr.y = lo;                            \
                    if (wrp) p2o[(g * 4 + r) * 16 + ntl * 4] =                 \
                        __builtin_bit_cast(uint32_t, pr);                      \
                }                                                              \
            }                                                                  \
        }
        CONV2_EPI(accA, wv);
        CONV2_EPI(accB, wv + 4);
#undef CONV2_EPI
    }
    __syncthreads();

    // ---- fc1: 256 -> 120, relu : MFMA 16x16x32, exact hi/lo ----
    {
        const int cn = lane & 15, g4 = lane >> 4;
        const uint2* apb = (const uint2*)(s_u32 + (cn & 7) * 260);
        const uint4* bw0 = ws4 + (size_t)wv * 2048 + lane;
        const uint4* bw1 = ws4 + (size_t)(wv + 4) * 2048 + lane;
        floatx4 acc0 = {0.f,0.f,0.f,0.f}, acc1 = {0.f,0.f,0.f,0.f};
#pragma unroll 4
        for (int ks = 0; ks < 32; ++ks) {
            uint2 a2 = apb[ks * 4 + g4];         // pairs (k0,k1), k0 = ks*8+g4*2
            union { half8 h; uint32_t u[4]; } af;
            af.u[0] = a2.x; af.u[1] = a2.x; af.u[2] = a2.y; af.u[3] = a2.y;
            union { half8 h; uint4 u; } b0, b1;
            b0.u = bw0[ks * 64]; b1.u = bw1[ks * 64];
            acc0 = __builtin_amdgcn_mfma_f32_16x16x32_f16(af.h, b0.h, acc0, 0,0,0);
            acc1 = __builtin_amdgcn_mfma_f32_16x16x32_f16(af.h, b1.h, acc1, 0,0,0);
        }
        // store (hi,lo) pairs; o>=120 -> 0 (zero-pads fc2's K)
#pragma unroll
        for (int t = 0; t < 2; ++t) {
            int o = (wv + 4 * t) * 16 + cn;
            floatx4 a = t ? acc1 : acc0;
            float bias = (o < 120) ? fb1[o] : 0.f;
            if (g4 < 2) {
#pragma unroll
                for (int r = 0; r < 4; ++r) {
                    int inst = g4 * 4 + r;
                    float v = fmaxf(a[r] + bias, 0.f);
                    if (o >= 120) v = 0.f;
                    _Float16 hi = (_Float16)v;
                    _Float16 lo = (_Float16)(v - (float)hi);
                    f16x2 pr; pr.x = hi; pr.y = lo;
                    s_u32[2080 + inst * 132 + o] = __builtin_bit_cast(uint32_t, pr);
                }
            }
        }
    }
    __syncthreads();

    // ---- fc2: 120 -> 84, relu : MFMA 16x16x32, exact hi/lo ----
    {
        const int cn = lane & 15, g4 = lane >> 4;
        const uint2* apb = (const uint2*)(s_u32 + 2080 + (cn & 7) * 132);
        const uint4* wsf2 = ws4 + 16384;
        const uint4* bw0 = wsf2 + (size_t)wv * 1024 + lane;
        const uint4* bw1 = wsf2 + (size_t)(wv + 4) * 1024 + lane;
        const bool has1 = wv < 2;
        floatx4 acc0 = {0.f,0.f,0.f,0.f}, acc1 = {0.f,0.f,0.f,0.f};
#pragma unroll 4
        for (int ks = 0; ks < 16; ++ks) {
            uint2 a2 = apb[ks * 4 + g4];
            union { half8 h; uint32_t u[4]; } af;
            af.u[0] = a2.x; af.u[1] = a2.x; af.u[2] = a2.y; af.u[3] = a2.y;
            union { half8 h; uint4 u; } b0;
            b0.u = bw0[ks * 64];
            acc0 = __builtin_amdgcn_mfma_f32_16x16x32_f16(af.h, b0.h, acc0, 0,0,0);
            if (has1) {
                union { half8 h; uint4 u; } b1;
                b1.u = bw1[ks * 64];
                acc1 = __builtin_amdgcn_mfma_f32_16x16x32_f16(af.h, b1.h, acc1, 0,0,0);
            }
        }
        float* s_f2 = (float*)(s_u32 + 3136);
#pragma unroll
        for (int t = 0; t < 2; ++t) {
            if (t && !has1) break;
            int o = (wv + 4 * t) * 16 + cn;
            floatx4 a = t ? acc1 : acc0;
            if (o < 84 && g4 < 2) {
                float bias = fb2[o];
#pragma unroll
                for (int r = 0; r < 4; ++r) {
                    int inst = g4 * 4 + r;
                    s_f2[inst * 84 + o] = fmaxf(a[r] + bias, 0.f);
                }
            }
        }
    }
    __syncthreads();

    // ---- fc3: 84 -> 10. 80 lanes ----
    if (tid < 80) {
        int o    = tid % 10;
        int inst = tid / 10;                     // 0..7
        const float4* wr = (const float4*)(fw3 + o * 84);
        const float4* q0 = (const float4*)(s_pool + 3136 + inst * 84);
        float a0 = 0.f;
#pragma unroll
        for (int k = 0; k < 21; ++k) {
            float4 w4 = wr[k];
            float4 p = q0[k];
            a0 = fmaf(w4.x,p.x,a0); a0 = fmaf(w4.y,p.y,a0); a0 = fmaf(w4.z,p.z,a0); a0 = fmaf(w4.w,p.w,a0);
        }
        s_log[inst * 10 + o] = a0 + fb3[o];
    }
    __syncthreads();

    // ---- softmax (in-lane) + full convolution (len 19) + log ----
    if (tid < 19 * SPB) {
        int ls = tid / 19;                       // sample 0..3
        int t  = tid % 19;
        const float* la = &s_log[(ls * 2 + 0) * 10];
        const float* lb = &s_log[(ls * 2 + 1) * 10];
        float pa[10], pb[10];
        float mxa = la[0], mxb = lb[0];
#pragma unroll
        for (int j = 1; j < 10; ++j) { mxa = fmaxf(mxa, la[j]); mxb = fmaxf(mxb, lb[j]); }
        float sa = 0.f, sb = 0.f;
#pragma unroll
        for (int j = 0; j < 10; ++j) {
            pa[j] = __expf(la[j] - mxa); sa += pa[j];
            pb[j] = __expf(lb[j] - mxb); sb += pb[j];
        }
        float inv = 1.f / (sa * sb);
        int jlo = t - 9 > 0 ? t - 9 : 0;
        int jhi = t < 9 ? t : 9;
        float z = 0.f;
        for (int j = jlo; j <= jhi; ++j)
            z += pa[j] * pb[t - j];
        out[(size_t)(b0 + ls) * 19 + t] = __logf(z * inv);
    }
}

extern "C" void kernel_launch(void* const* d_in, const int* in_sizes, int n_in,
                              void* d_out, int out_size, void* d_ws, size_t ws_size,
                              hipStream_t stream) {
    const float* x   = (const float*)d_in[0];
    const float* cw1 = (const float*)d_in[1];
    const float* cb1 = (const float*)d_in[2];
    const float* cw2 = (const float*)d_in[3];
    const float* cb2 = (const float*)d_in[4];
    const float* fw1 = (const float*)d_in[5];
    const float* fb1 = (const float*)d_in[6];
    const float* fw2 = (const float*)d_in[7];
    const float* fb2 = (const float*)d_in[8];
    const float* fw3 = (const float*)d_in[9];
    const float* fb3 = (const float*)d_in[10];
    float* out = (float*)d_out;
    uint4* ws4 = (uint4*)d_ws;                   // 368 KB used

    const int B = in_sizes[0] / (2 * 28 * 28);   // 16384

    prep_ws<<<(WS_TOT + 255) / 256, 256, 0, stream>>>(fw1, fw2, cw1, cw2, ws4);
    lenet_fused<<<B / SPB, 256, 0, stream>>>(x, cb1, cb2,
                                             fb1, fb2, fw3, fb3, ws4, out);
}